// Round 4
// baseline (52.806 us; speedup 1.0000x reference)
//
#include <hip/hip_runtime.h>

typedef _Float16 f16;
typedef _Float16 f16x2 __attribute__((ext_vector_type(2)));
typedef _Float16 f16x8 __attribute__((ext_vector_type(8)));
typedef float f32x4 __attribute__((ext_vector_type(4)));
typedef unsigned int u32;

union U2 { u32 u; f16x2 h; };
union AF { f16x8 v; u32 u[4]; };

__device__ __forceinline__ u32 dup16(float f) {
    U2 a; f16 h = (f16)f; a.h = f16x2{h, h}; return a.u;
}

// ---------------- fused pre kernel ----------------
// blocks 0..63:   C/A columns (j = 64+h) of Wfrag, h = blk
// blocks 64..127: W1 columns (j = h), h = blk-64
// block 128:      rvec + cnst
__global__ __launch_bounds__(256) void pre_all(
    const float* __restrict__ W1, const float* __restrict__ b1,
    const float* __restrict__ W2, const float* __restrict__ b2,
    const float* __restrict__ W3, const float* __restrict__ b3,
    const float* __restrict__ W_out, const float* __restrict__ b_out,
    f16* __restrict__ Wfrag, float* __restrict__ rvec, float* __restrict__ cnst) {
    const int blk = blockIdx.x, t = threadIdx.x;
    if (blk < 64) {
        const int h = blk;
        __shared__ float w3e[2048];  // W3eff[o][q]
        __shared__ float w2s[2048];  // W2[o][h][p]
        __shared__ float wo2[64];
#pragma unroll
        for (int i = 0; i < 8; ++i) {
            int idx = t + 256 * i;
            w2s[idx] = W2[((idx >> 5) * 64 + h) * 32 + (idx & 31)];
            float s = 0.f;
            for (int o3 = 0; o3 < 64; ++o3)
                s += W_out[128 + o3] * W3[o3 * 2048 + idx];
            w3e[idx] = s;
        }
        if (t < 64) wo2[t] = W_out[64 + t];
        __syncthreads();
        for (int idx = t; idx < 1056; idx += 256) {
            int c = idx >> 5, g = (idx >> 3) & 3, b = idx & 7;
            int kk = 4 * g + (b & 3) + 16 * (b >> 2);
            int k = 32 * c + kk;
            float val = 0.f;
            if (k < 1024) {
                int p = k >> 5, q = k & 31;
                for (int o = 0; o < 64; ++o)
                    val += w3e[o * 32 + q] * w2s[o * 32 + p];
            } else {
                int mm = k - 1024;
                for (int o = 0; o < 64; ++o)
                    val += wo2[o] * w2s[o * 32 + mm];
            }
            int t4 = 4 + (h >> 4);
            int l = 16 * g + (h & 15);
            Wfrag[((c * 8 + t4) * 64 + l) * 8 + b] = (f16)val;
        }
    } else if (blk < 128) {
        const int h = blk - 64;
        for (int idx = t; idx < 1056; idx += 256) {
            int c = idx >> 5, g = (idx >> 3) & 3, b = idx & 7;
            int kk = 4 * g + (b & 3) + 16 * (b >> 2);
            int k = 32 * c + kk;
            float val = (k < 1024) ? W1[h * 1024 + k] : 0.f;
            int t4 = h >> 4;
            int l = 16 * g + (h & 15);
            Wfrag[((c * 8 + t4) * 64 + l) * 8 + b] = (f16)val;
        }
    } else {
        __shared__ float part[256];
        int m = t & 31, og = t >> 5;  // [0,8)
        float s = 0.f;
        for (int oo = 0; oo < 8; ++oo) {
            int o = og * 8 + oo;
            float ah = 0.f;
            for (int hh = 0; hh < 64; ++hh)
                ah += b2[hh] * W3[(o * 64 + hh) * 32 + m];
            s += W_out[128 + o] * ah;
        }
        part[t] = s;
        __syncthreads();
        if (t < 32) {
            float r = 0.f;
#pragma unroll
            for (int og2 = 0; og2 < 8; ++og2) r += part[og2 * 32 + t];
            rvec[t] = r;
        }
        if (t == 32) {
            float s2 = 0.f;
            for (int o = 0; o < 64; ++o)
                s2 += b1[o] * W_out[o] + b2[o] * W_out[64 + o] + b3[o] * W_out[128 + o];
            cnst[0] = b_out[0] + 64.f * s2;
        }
    }
}

// ---------------- main kernel ----------------

#define EPOS(row, col) ((row) * 64 + (((col) + 4 * (row)) & 63))

// Block: 2 batches (128 rows) x 128 cols, 4 waves. Wave (wr,wc): batch wr
// (rows 64wr..64wr+63), cols [64wc,64wc+63]. 4 strips x 4 col-tiles 16x16x32.
__global__ __launch_bounds__(256, 3) void cin_main(
    const float* __restrict__ x0, const f16* __restrict__ Wfrag,
    const float* __restrict__ b1, const float* __restrict__ W_out,
    const float* __restrict__ rvec, const float* __restrict__ cnst,
    float* __restrict__ out) {
    __shared__ u32 xdup[2 * 32 * 64];   // [bl][m][l][j] = dup16(x[bl][m][16j+l])
    __shared__ float eps[2][16 * 64];   // epilogue strip exchange (swizzled)
    __shared__ float b1s[64], w1s[64], rs[32], rvb[2], obuf[2][2];

    const int t = threadIdx.x;
    const int w = t >> 6, lane = t & 63;
    const int wr = w >> 1, wc = w & 1;
    const int g = (lane >> 4) & 3, l15 = lane & 15;
    const int blk = blockIdx.x;

    {  // stage x0 (2 batches) -> xdup, transposed-quad layout
        const float* src = x0 + (size_t)blk * 4096;
        const int l = t & 15, row = t >> 4;
#pragma unroll
        for (int it = 0; it < 4; ++it) {
            int rm = it * 16 + row;  // bl*32+m
            uint4 dv;
            dv.x = dup16(src[rm * 64 + 0  + l]);
            dv.y = dup16(src[rm * 64 + 16 + l]);
            dv.z = dup16(src[rm * 64 + 32 + l]);
            dv.w = dup16(src[rm * 64 + 48 + l]);
            *reinterpret_cast<uint4*>(&xdup[rm * 64 + l * 4]) = dv;
        }
    }
    if (t < 64) { b1s[t] = b1[t]; w1s[t] = W_out[t]; }
    if (t >= 64 && t < 96) rs[t - 64] = rvec[t - 64];
    __syncthreads();

    // xp[s][i]: packed {x[m0][d], x[m0+1][d]}, d = 16s + l15, batch wr
    f16x2 xp[4][4];
#pragma unroll
    for (int s = 0; s < 4; ++s) {
        int base = wr * 2048 + l15 * 4 + s;
#pragma unroll
        for (int i = 0; i < 4; ++i) {
            int m0 = 4 * g + 2 * (i & 1) + 16 * (i >> 1);
            u32 lo = xdup[base + m0 * 64];
            u32 hi = xdup[base + (m0 + 1) * 64];
            U2 p; p.u = (lo & 0xffffu) | (hi << 16);
            xp[s][i] = p.h;
        }
    }

    f32x4 acc[4][4];
#pragma unroll
    for (int s = 0; s < 4; ++s)
#pragma unroll
        for (int tt = 0; tt < 4; ++tt) acc[s][tt] = f32x4{0.f, 0.f, 0.f, 0.f};

    const f16x8* Wg = reinterpret_cast<const f16x8*>(Wfrag);
    f16x8 bfA[4], bfB[4];
#pragma unroll
    for (int tt = 0; tt < 4; ++tt)
        bfA[tt] = Wg[(wc * 4 + tt) * 64 + lane];

#define CHUNK_BODY(cc, bfr)                                                  \
    do {                                                                     \
        uint4 q0 = *reinterpret_cast<const uint4*>(                          \
            &xdup[wr * 2048 + (cc) * 64 + l15 * 4]);                         \
        u32 qs[4] = {q0.x, q0.y, q0.z, q0.w};                                \
        _Pragma("unroll")                                                    \
        for (int s = 0; s < 4; ++s) {                                        \
            U2 sc; sc.u = qs[s];                                             \
            AF af;                                                           \
            _Pragma("unroll")                                                \
            for (int i = 0; i < 4; ++i) {                                    \
                U2 pp; pp.h = sc.h * xp[s][i];                               \
                af.u[i] = pp.u;                                              \
            }                                                                \
            __builtin_amdgcn_s_setprio(1);                                   \
            _Pragma("unroll")                                                \
            for (int tt = 0; tt < 4; ++tt)                                   \
                acc[s][tt] = __builtin_amdgcn_mfma_f32_16x16x32_f16(         \
                    af.v, bfr[tt], acc[s][tt], 0, 0, 0);                     \
            __builtin_amdgcn_s_setprio(0);                                   \
        }                                                                    \
    } while (0)

    for (int c = 0; c < 32; c += 2) {
#pragma unroll
        for (int tt = 0; tt < 4; ++tt)
            bfB[tt] = Wg[((c + 1) * 8 + wc * 4 + tt) * 64 + lane];
        CHUNK_BODY(c, bfA);
#pragma unroll
        for (int tt = 0; tt < 4; ++tt)
            bfA[tt] = Wg[((c + 2) * 8 + wc * 4 + tt) * 64 + lane];
        CHUNK_BODY(c + 1, bfB);
    }
    {  // chunk 32: linear-v part (A = xp), fragments already in bfA
#pragma unroll
        for (int s = 0; s < 4; ++s) {
            AF af;
#pragma unroll
            for (int i = 0; i < 4; ++i) { U2 pp; pp.h = xp[s][i]; af.u[i] = pp.u; }
            __builtin_amdgcn_s_setprio(1);
#pragma unroll
            for (int tt = 0; tt < 4; ++tt)
                acc[s][tt] = __builtin_amdgcn_mfma_f32_16x16x32_f16(
                    af.v, bfA[tt], acc[s][tt], 0, 0, 0);
            __builtin_amdgcn_s_setprio(0);
        }
    }
#undef CHUNK_BODY

    // ---- rv term: wc==0 wave handles batch wr; lane <-> d (conflict-free)
    if (wc == 0) {
        float sum = 0.f;
        int base = wr * 2048 + (lane & 15) * 4 + (lane >> 4);
#pragma unroll
        for (int m = 0; m < 32; ++m) {
            U2 v; v.u = xdup[base + m * 64];
            sum += rs[m] * (float)v.h[0];
        }
#pragma unroll
        for (int off = 32; off; off >>= 1) sum += __shfl_xor(sum, off);
        if (lane == 0) rvb[wr] = sum;
    }

    // ---- epilogue: s(b,d) = sum_h A1*(w1+A2) + b1*A2   (+ b1*w1 in cnst)
    float bs = 0.f;
#pragma unroll
    for (int s = 0; s < 4; ++s) {
        if (wc == 1) {
#pragma unroll
            for (int tt = 0; tt < 4; ++tt) {
                float w1v = w1s[16 * tt + l15];
                float b1v = b1s[16 * tt + l15];
#pragma unroll
                for (int r = 0; r < 4; ++r) {
                    float a = acc[s][tt][r];
                    eps[wr][EPOS(4 * g + r, 16 * tt + l15)] = a + w1v;
                    bs += b1v * a;
                }
            }
        }
        __syncthreads();
        if (wc == 0) {
#pragma unroll
            for (int tt = 0; tt < 4; ++tt)
#pragma unroll
                for (int r = 0; r < 4; ++r)
                    bs += acc[s][tt][r] * eps[wr][EPOS(4 * g + r, 16 * tt + l15)];
        }
        __syncthreads();
    }
#pragma unroll
    for (int off = 32; off; off >>= 1) bs += __shfl_xor(bs, off);
    if (lane == 0) obuf[wr][wc] = bs;
    __syncthreads();
    if (t < 2)
        out[blk * 2 + t] = cnst[0] + rvb[t] + obuf[t][0] + obuf[t][1];
}

extern "C" void kernel_launch(void* const* d_in, const int* in_sizes, int n_in,
                              void* d_out, int out_size, void* d_ws, size_t ws_size,
                              hipStream_t stream) {
    const float* x0    = (const float*)d_in[0];
    const float* W1    = (const float*)d_in[1];
    const float* b1    = (const float*)d_in[2];
    const float* W2    = (const float*)d_in[3];
    const float* b2    = (const float*)d_in[4];
    const float* W3    = (const float*)d_in[5];
    const float* b3    = (const float*)d_in[6];
    const float* W_out = (const float*)d_in[7];
    const float* b_out = (const float*)d_in[8];

    char* wsb = (char*)d_ws;
    f16*   Wfrag = (f16*)wsb;                       // 135168 halves = 270336 B
    float* rvecp = (float*)(wsb + 270336);          // 32
    float* cnstp = rvecp + 32;                      // 1
    float* outp  = (float*)d_out;

    hipLaunchKernelGGL(pre_all,  dim3(129),  dim3(256), 0, stream,
                       W1, b1, W2, b2, W3, b3, W_out, b_out, Wfrag, rvecp, cnstp);
    hipLaunchKernelGGL(cin_main, dim3(1024), dim3(256), 0, stream,
                       x0, Wfrag, b1, W_out, rvecp, cnstp, outp);
}

// Round 6
// 45.597 us; speedup vs baseline: 1.1581x; 1.1581x over previous
//
#include <hip/hip_runtime.h>

typedef _Float16 f16;
typedef _Float16 f16x2 __attribute__((ext_vector_type(2)));
typedef __fp16 fp16x2 __attribute__((ext_vector_type(2)));
typedef _Float16 f16x8 __attribute__((ext_vector_type(8)));
typedef float f32x4 __attribute__((ext_vector_type(4)));
typedef unsigned int u32;

union U2 { u32 u; f16x2 h; fp16x2 h2; };
union AF { f16x8 v; u32 u[4]; };

// ---------------- fused pre kernel ----------------
// Symmetric-folded K enumeration: chunk c = 2*sg + par (sg in [0,8]), slot kk:
//   A = kk>>1, z = kk&1, B = (A+sg)&15
//   a = 2A + (par ? 1-z : z), bq = 2B + z
//   sg==0 && par==1 && z==1          -> weight 0 (duplicate)
//   sg==8 && A>=8                    -> linear slot, m = par ? kk-16 : kk
//   else a==bq -> Wcat[a,a]; a!=bq   -> Wcat[a,bq]+Wcat[bq,a]
// blocks 0..63: C/A cols (j=64+h); 64..127: W1 cols (j=h); 128: rvec+cnst
__global__ __launch_bounds__(256) void pre_all(
    const float* __restrict__ W1, const float* __restrict__ b1,
    const float* __restrict__ W2, const float* __restrict__ b2,
    const float* __restrict__ W3, const float* __restrict__ b3,
    const float* __restrict__ W_out, const float* __restrict__ b_out,
    f16* __restrict__ Wfrag, float* __restrict__ rvec, float* __restrict__ cnst) {
    const int blk = blockIdx.x, t = threadIdx.x;
    if (blk < 64) {
        const int h = blk;
        __shared__ float w3e[2048];  // W3eff[o][q]
        __shared__ float w2s[2048];  // W2[o][h][p]
        __shared__ float wo2[64];
#pragma unroll
        for (int i = 0; i < 8; ++i) {
            int idx = t + 256 * i;
            w2s[idx] = W2[((idx >> 5) * 64 + h) * 32 + (idx & 31)];
            float s = 0.f;
            for (int o3 = 0; o3 < 64; ++o3)
                s += W_out[128 + o3] * W3[o3 * 2048 + idx];
            w3e[idx] = s;
        }
        if (t < 64) wo2[t] = W_out[64 + t];
        __syncthreads();
        for (int idx = t; idx < 576; idx += 256) {
            int c = idx >> 5, kk = idx & 31;
            int sg = c >> 1, par = c & 1, A = kk >> 1, z = kk & 1;
            int B = (A + sg) & 15;
            float val = 0.f;
            if (sg == 0 && par == 1 && z == 1) {
                val = 0.f;
            } else if (sg == 8 && A >= 8) {
                int m = par ? (kk - 16) : kk;
                float s = 0.f;
                for (int o = 0; o < 64; ++o) s += wo2[o] * w2s[o * 32 + m];
                val = s;
            } else {
                int a = 2 * A + (par ? (1 - z) : z);
                int bq = 2 * B + z;
                float s = 0.f;
                if (a == bq) {
                    for (int o = 0; o < 64; ++o)
                        s += w3e[o * 32 + a] * w2s[o * 32 + a];
                } else {
                    for (int o = 0; o < 64; ++o)
                        s += w3e[o * 32 + bq] * w2s[o * 32 + a] +
                             w3e[o * 32 + a] * w2s[o * 32 + bq];
                }
                val = s;
            }
            int g = (kk >> 2) & 3, bb = (kk & 3) + 4 * (kk >> 4);
            int t4 = 4 + (h >> 4), l = 16 * g + (h & 15);
            Wfrag[((c * 8 + t4) * 64 + l) * 8 + bb] = (f16)val;
        }
    } else if (blk < 128) {
        const int h = blk - 64;
        __shared__ float w1r[1024];
        for (int i = t; i < 1024; i += 256) w1r[i] = W1[h * 1024 + i];
        __syncthreads();
        for (int idx = t; idx < 576; idx += 256) {
            int c = idx >> 5, kk = idx & 31;
            int sg = c >> 1, par = c & 1, A = kk >> 1, z = kk & 1;
            int B = (A + sg) & 15;
            float val = 0.f;
            if ((sg == 0 && par == 1 && z == 1) || (sg == 8 && A >= 8)) {
                val = 0.f;  // duplicate slot or linear slot (no W1 part)
            } else {
                int a = 2 * A + (par ? (1 - z) : z);
                int bq = 2 * B + z;
                val = (a == bq) ? w1r[33 * a] : (w1r[32 * a + bq] + w1r[32 * bq + a]);
            }
            int g = (kk >> 2) & 3, bb = (kk & 3) + 4 * (kk >> 4);
            int t4 = h >> 4, l = 16 * g + (h & 15);
            Wfrag[((c * 8 + t4) * 64 + l) * 8 + bb] = (f16)val;
        }
    } else {
        __shared__ float part[256];
        int m = t & 31, og = t >> 5;
        float s = 0.f;
        for (int oo = 0; oo < 8; ++oo) {
            int o = og * 8 + oo;
            float ah = 0.f;
            for (int hh = 0; hh < 64; ++hh)
                ah += b2[hh] * W3[(o * 64 + hh) * 32 + m];
            s += W_out[128 + o] * ah;
        }
        part[t] = s;
        __syncthreads();
        if (t < 32) {
            float r = 0.f;
#pragma unroll
            for (int og2 = 0; og2 < 8; ++og2) r += part[og2 * 32 + t];
            rvec[t] = r;
        }
        if (t == 32) {
            float s2 = 0.f;
            for (int o = 0; o < 64; ++o)
                s2 += b1[o] * W_out[o] + b2[o] * W_out[64 + o] + b3[o] * W_out[128 + o];
            cnst[0] = b_out[0] + 64.f * s2;
        }
    }
}

// ---------------- main kernel ----------------

#define EPOS(row, col) ((row) * 64 + (((col) + 4 * (row)) & 63))

// FQ[bl][J][d]: uint2 { E[(2J)%32][d], E[(2J+2)%32][d] }, J in [0,32) (J>=16
// duplicates J-16), E[m] = pack_f16(v_m, v_{m+1}). Row stride 130 u32 (pad).
__global__ __launch_bounds__(256, 3) void cin_main(
    const float* __restrict__ x0, const f16* __restrict__ Wfrag,
    const float* __restrict__ b1, const float* __restrict__ W_out,
    const float* __restrict__ rvec, const float* __restrict__ cnst,
    float* __restrict__ out) {
    __shared__ __align__(16) u32 FQ[2 * 32 * 130];  // 33280 B
    __shared__ float eps[2][16 * 64];
    __shared__ float b1s[64], w1s[64], rs[32], rvb[2], obuf[2][2];

    const int t = threadIdx.x;
    const int w = t >> 6, lane = t & 63;
    const int wr = w >> 1, wc = w & 1;
    const int g = (lane >> 4) & 3, l15 = lane & 15;
    const int blk = blockIdx.x;

    {   // stage x0 (2 batches) -> FQ quads, single pass
        const float* src = x0 + (size_t)blk * 4096;
        const int J = t >> 4, l = t & 15;  // J in [0,16)
        int r0 = 2 * J, r1 = 2 * J + 1, r2 = (2 * J + 2) & 31, r3 = (2 * J + 3) & 31;
#pragma unroll
        for (int bl = 0; bl < 2; ++bl) {
            const float* sb = src + bl * 2048;
#pragma unroll
            for (int k2 = 0; k2 < 4; ++k2) {
                int d = 16 * k2 + l;
                U2 u0, u1;
                u0.h2 = __builtin_amdgcn_cvt_pkrtz(sb[r0 * 64 + d], sb[r1 * 64 + d]);
                u1.h2 = __builtin_amdgcn_cvt_pkrtz(sb[r2 * 64 + d], sb[r3 * 64 + d]);
                uint2 ent; ent.x = u0.u; ent.y = u1.u;
                int base = bl * 4160 + J * 130 + 2 * d;
                *reinterpret_cast<uint2*>(&FQ[base]) = ent;
                *reinterpret_cast<uint2*>(&FQ[base + 2080]) = ent;  // J+16 copy
            }
        }
    }
    if (t < 64) { b1s[t] = b1[t]; w1s[t] = W_out[t]; }
    if (t >= 64 && t < 96) rs[t - 64] = rvec[t - 64];
    __syncthreads();

    // single hoisted LDS address; every read = v1base + compile-time imm
    const int v1base = wr * 4160 + 260 * g + 2 * l15;

    U2 xp[4][4], xpsw[4][4];
#pragma unroll
    for (int s = 0; s < 4; ++s) {
        uint2 qa = *reinterpret_cast<const uint2*>(&FQ[v1base + 32 * s]);
        uint2 qb = *reinterpret_cast<const uint2*>(&FQ[v1base + 32 * s + 1040]);
        xp[s][0].u = qa.x; xp[s][1].u = qa.y; xp[s][2].u = qb.x; xp[s][3].u = qb.y;
#pragma unroll
        for (int i = 0; i < 4; ++i)
            xpsw[s][i].u = (xp[s][i].u >> 16) | (xp[s][i].u << 16);
    }

    f32x4 acc[4][4];
#pragma unroll
    for (int s = 0; s < 4; ++s)
#pragma unroll
        for (int tt = 0; tt < 4; ++tt) acc[s][tt] = f32x4{0.f, 0.f, 0.f, 0.f};

    const f16x8* Wg = reinterpret_cast<const f16x8*>(Wfrag);
    f16x8 bfA[4], bfB[4];
#pragma unroll
    for (int tt = 0; tt < 4; ++tt) bfA[tt] = Wg[(wc * 4 + tt) * 64 + lane];

#define PKU(xa, ub) ({ U2 b_; b_.u = (ub); U2 r_; r_.h = (xa).h * b_.h; r_.u; })

#define PREF(dst, cc) { _Pragma("unroll") for (int tt = 0; tt < 4; ++tt) \
    dst[tt] = Wg[((cc) * 8 + wc * 4 + tt) * 64 + lane]; }

#define BODY(cc, bfr) { \
    _Pragma("unroll") \
    for (int s = 0; s < 4; ++s) { \
        AF af; \
        if ((cc) == 0) { \
            _Pragma("unroll") \
            for (int i = 0; i < 4; ++i) af.u[i] = PKU(xp[s][i], xp[s][i].u); \
        } else if ((cc) == 1) { \
            _Pragma("unroll") \
            for (int i = 0; i < 4; ++i) af.u[i] = PKU(xpsw[s][i], xp[s][i].u); \
        } else if ((cc) < 16) { \
            uint2 qa = *reinterpret_cast<const uint2*>(&FQ[v1base + 32 * s + ((cc) >> 1) * 130]); \
            uint2 qb = *reinterpret_cast<const uint2*>(&FQ[v1base + 32 * s + 1040 + ((cc) >> 1) * 130]); \
            if ((cc) & 1) { \
                af.u[0] = PKU(xpsw[s][0], qa.x); af.u[1] = PKU(xpsw[s][1], qa.y); \
                af.u[2] = PKU(xpsw[s][2], qb.x); af.u[3] = PKU(xpsw[s][3], qb.y); \
            } else { \
                af.u[0] = PKU(xp[s][0], qa.x); af.u[1] = PKU(xp[s][1], qa.y); \
                af.u[2] = PKU(xp[s][2], qb.x); af.u[3] = PKU(xp[s][3], qb.y); \
            } \
        } else if ((cc) == 16) { \
            uint2 qa = *reinterpret_cast<const uint2*>(&FQ[v1base + 32 * s + 1040]); \
            af.u[0] = PKU(xp[s][0], qa.x); af.u[1] = PKU(xp[s][1], qa.y); \
            af.u[2] = xp[s][2].u; af.u[3] = xp[s][3].u; \
        } else { \
            uint2 qa = *reinterpret_cast<const uint2*>(&FQ[v1base + 32 * s + 1040]); \
            af.u[0] = PKU(xpsw[s][0], qa.x); af.u[1] = PKU(xpsw[s][1], qa.y); \
            af.u[2] = xp[s][0].u; af.u[3] = xp[s][1].u; \
        } \
        __builtin_amdgcn_s_setprio(1); \
        _Pragma("unroll") \
        for (int tt = 0; tt < 4; ++tt) \
            acc[s][tt] = __builtin_amdgcn_mfma_f32_16x16x32_f16(af.v, bfr[tt], acc[s][tt], 0, 0, 0); \
        __builtin_amdgcn_s_setprio(0); \
    } }

    PREF(bfB, 1);  BODY(0, bfA);
    PREF(bfA, 2);  BODY(1, bfB);
    PREF(bfB, 3);  BODY(2, bfA);
    PREF(bfA, 4);  BODY(3, bfB);
    PREF(bfB, 5);  BODY(4, bfA);
    PREF(bfA, 6);  BODY(5, bfB);
    PREF(bfB, 7);  BODY(6, bfA);
    PREF(bfA, 8);  BODY(7, bfB);
    PREF(bfB, 9);  BODY(8, bfA);
    PREF(bfA, 10); BODY(9, bfB);
    PREF(bfB, 11); BODY(10, bfA);
    PREF(bfA, 12); BODY(11, bfB);
    PREF(bfB, 13); BODY(12, bfA);
    PREF(bfA, 14); BODY(13, bfB);
    PREF(bfB, 15); BODY(14, bfA);
    PREF(bfA, 16); BODY(15, bfB);
    PREF(bfB, 17); BODY(16, bfA);
    BODY(17, bfB);

#undef BODY
#undef PREF
#undef PKU

    // ---- rv term: wc==0 wave handles batch wr
    if (wc == 0) {
        float sum = 0.f;
#pragma unroll
        for (int J = 0; J < 16; ++J) {
            U2 v; v.u = FQ[wr * 4160 + J * 130 + 2 * lane];
            sum += rs[2 * J] * (float)v.h[0] + rs[2 * J + 1] * (float)v.h[1];
        }
#pragma unroll
        for (int off = 32; off; off >>= 1) sum += __shfl_xor(sum, off);
        if (lane == 0) rvb[wr] = sum;
    }

    // ---- epilogue: s(b,d) = sum_h A1*(w1+A2) + b1*A2   (+ b1*w1 in cnst)
    float bs = 0.f;
#pragma unroll
    for (int s = 0; s < 4; ++s) {
        if (wc == 1) {
#pragma unroll
            for (int tt = 0; tt < 4; ++tt) {
                float w1v = w1s[16 * tt + l15];
                float b1v = b1s[16 * tt + l15];
#pragma unroll
                for (int r = 0; r < 4; ++r) {
                    float a = acc[s][tt][r];
                    eps[wr][EPOS(4 * g + r, 16 * tt + l15)] = a + w1v;
                    bs += b1v * a;
                }
            }
        }
        __syncthreads();
        if (wc == 0) {
#pragma unroll
            for (int tt = 0; tt < 4; ++tt)
#pragma unroll
                for (int r = 0; r < 4; ++r)
                    bs += acc[s][tt][r] * eps[wr][EPOS(4 * g + r, 16 * tt + l15)];
        }
        __syncthreads();
    }
#pragma unroll
    for (int off = 32; off; off >>= 1) bs += __shfl_xor(bs, off);
    if (lane == 0) obuf[wr][wc] = bs;
    __syncthreads();
    if (t < 2)
        out[blk * 2 + t] = cnst[0] + rvb[t] + obuf[t][0] + obuf[t][1];
}

extern "C" void kernel_launch(void* const* d_in, const int* in_sizes, int n_in,
                              void* d_out, int out_size, void* d_ws, size_t ws_size,
                              hipStream_t stream) {
    const float* x0    = (const float*)d_in[0];
    const float* W1    = (const float*)d_in[1];
    const float* b1    = (const float*)d_in[2];
    const float* W2    = (const float*)d_in[3];
    const float* b2    = (const float*)d_in[4];
    const float* W3    = (const float*)d_in[5];
    const float* b3    = (const float*)d_in[6];
    const float* W_out = (const float*)d_in[7];
    const float* b_out = (const float*)d_in[8];

    char* wsb = (char*)d_ws;
    f16*   Wfrag = (f16*)wsb;                       // 18*4096 halves = 147456 B
    float* rvecp = (float*)(wsb + 147456);          // 32
    float* cnstp = rvecp + 32;                      // 1
    float* outp  = (float*)d_out;

    hipLaunchKernelGGL(pre_all,  dim3(129),  dim3(256), 0, stream,
                       W1, b1, W2, b2, W3, b3, W_out, b_out, Wfrag, rvecp, cnstp);
    hipLaunchKernelGGL(cin_main, dim3(1024), dim3(256), 0, stream,
                       x0, Wfrag, b1, W_out, rvecp, cnstp, outp);
}

// Round 7
// 40.814 us; speedup vs baseline: 1.2938x; 1.1172x over previous
//
#include <hip/hip_runtime.h>

typedef _Float16 f16;
typedef _Float16 f16x2 __attribute__((ext_vector_type(2)));
typedef __fp16 fp16x2 __attribute__((ext_vector_type(2)));
typedef _Float16 f16x8 __attribute__((ext_vector_type(8)));
typedef float f32x4 __attribute__((ext_vector_type(4)));
typedef unsigned int u32;

union U2 { u32 u; f16x2 h; fp16x2 h2; };
union AF { f16x8 v; u32 u[4]; };

// ---------------- pre kernel 1: W3eff (computed ONCE, coalesced, MLP'd) ----
__global__ __launch_bounds__(256) void pre_w3eff(
    const float* __restrict__ W3, const float* __restrict__ W_out,
    float* __restrict__ W3eff) {
    const int idx = blockIdx.x * 256 + threadIdx.x;  // 2048 = (h,m)
    float acc[8] = {0.f, 0.f, 0.f, 0.f, 0.f, 0.f, 0.f, 0.f};
#pragma unroll
    for (int ob = 0; ob < 8; ++ob)
#pragma unroll
        for (int oi = 0; oi < 8; ++oi) {
            int o = ob * 8 + oi;
            acc[oi] += W_out[128 + o] * W3[o * 2048 + idx];
        }
    float s = 0.f;
#pragma unroll
    for (int oi = 0; oi < 8; ++oi) s += acc[oi];
    W3eff[idx] = s;
}

// ---------------- pre kernel 2: Wfrag + rvec + cnst ----------------
// Symmetric-folded K enumeration: chunk c = 2*sg + par (sg in [0,8]), slot kk:
//   A = kk>>1, z = kk&1, B = (A+sg)&15
//   a = 2A + (par ? 1-z : z), bq = 2B + z
//   sg==0 && par==1 && z==1          -> weight 0 (duplicate)
//   sg==8 && A>=8                    -> linear slot, m = par ? kk-16 : kk
//   else a==bq -> Wcat[a,a]; a!=bq   -> Wcat[a,bq]+Wcat[bq,a]
// blocks 0..63: C/A cols (j=64+h); 64..127: W1 cols (j=h); 128: rvec+cnst
__global__ __launch_bounds__(256) void pre_rest(
    const float* __restrict__ W1, const float* __restrict__ b1,
    const float* __restrict__ W2, const float* __restrict__ b2,
    const float* __restrict__ b3, const float* __restrict__ W_out,
    const float* __restrict__ b_out, const float* __restrict__ W3eff_g,
    f16* __restrict__ Wfrag, float* __restrict__ rvec, float* __restrict__ cnst) {
    const int blk = blockIdx.x, t = threadIdx.x;
    if (blk < 64) {
        const int h = blk;
        __shared__ float w3e[2048];  // W3eff[o][q]
        __shared__ float w2s[2048];  // W2[o][h][p]
        __shared__ float wo2[64];
#pragma unroll
        for (int i = 0; i < 8; ++i) {
            int idx = t + 256 * i;
            w3e[idx] = W3eff_g[idx];  // coalesced 8 KB
            w2s[idx] = W2[((idx >> 5) * 64 + h) * 32 + (idx & 31)];
        }
        if (t < 64) wo2[t] = W_out[64 + t];
        __syncthreads();
        for (int idx = t; idx < 576; idx += 256) {
            int c = idx >> 5, kk = idx & 31;
            int sg = c >> 1, par = c & 1, A = kk >> 1, z = kk & 1;
            int B = (A + sg) & 15;
            float val = 0.f;
            if (sg == 0 && par == 1 && z == 1) {
                val = 0.f;
            } else if (sg == 8 && A >= 8) {
                int m = par ? (kk - 16) : kk;
                float s = 0.f;
#pragma unroll 8
                for (int o = 0; o < 64; ++o) s += wo2[o] * w2s[o * 32 + m];
                val = s;
            } else {
                int a = 2 * A + (par ? (1 - z) : z);
                int bq = 2 * B + z;
                float s = 0.f;
                if (a == bq) {
#pragma unroll 8
                    for (int o = 0; o < 64; ++o)
                        s += w3e[o * 32 + a] * w2s[o * 32 + a];
                } else {
#pragma unroll 8
                    for (int o = 0; o < 64; ++o)
                        s += w3e[o * 32 + bq] * w2s[o * 32 + a] +
                             w3e[o * 32 + a] * w2s[o * 32 + bq];
                }
                val = s;
            }
            int g = (kk >> 2) & 3, bb = (kk & 3) + 4 * (kk >> 4);
            int t4 = 4 + (h >> 4), l = 16 * g + (h & 15);
            Wfrag[((c * 8 + t4) * 64 + l) * 8 + bb] = (f16)val;
        }
    } else if (blk < 128) {
        const int h = blk - 64;
        __shared__ float w1r[1024];
        for (int i = t; i < 1024; i += 256) w1r[i] = W1[h * 1024 + i];
        __syncthreads();
        for (int idx = t; idx < 576; idx += 256) {
            int c = idx >> 5, kk = idx & 31;
            int sg = c >> 1, par = c & 1, A = kk >> 1, z = kk & 1;
            int B = (A + sg) & 15;
            float val = 0.f;
            if ((sg == 0 && par == 1 && z == 1) || (sg == 8 && A >= 8)) {
                val = 0.f;  // duplicate slot or linear slot (no W1 part)
            } else {
                int a = 2 * A + (par ? (1 - z) : z);
                int bq = 2 * B + z;
                val = (a == bq) ? w1r[33 * a] : (w1r[32 * a + bq] + w1r[32 * bq + a]);
            }
            int g = (kk >> 2) & 3, bb = (kk & 3) + 4 * (kk >> 4);
            int t4 = h >> 4, l = 16 * g + (h & 15);
            Wfrag[((c * 8 + t4) * 64 + l) * 8 + bb] = (f16)val;
        }
    } else {
        // wave 0 (t<32): rvec[m] = sum_h b2[h] * W3eff[h][m]
        if (t < 32) {
            float acc[8] = {0.f, 0.f, 0.f, 0.f, 0.f, 0.f, 0.f, 0.f};
#pragma unroll
            for (int hb = 0; hb < 8; ++hb)
#pragma unroll
                for (int hi = 0; hi < 8; ++hi) {
                    int h = hb * 8 + hi;
                    acc[hi] += b2[h] * W3eff_g[h * 32 + t];
                }
            float r = 0.f;
#pragma unroll
            for (int hi = 0; hi < 8; ++hi) r += acc[hi];
            rvec[t] = r;
        }
        // wave 1 (t in [64,128)): cnst via wave-reduce
        if (t >= 64 && t < 128) {
            int o = t - 64;
            float v = b1[o] * W_out[o] + b2[o] * W_out[64 + o] +
                      b3[o] * W_out[128 + o];
#pragma unroll
            for (int off = 32; off; off >>= 1) v += __shfl_xor(v, off);
            if (o == 0) cnst[0] = b_out[0] + 64.f * v;
        }
    }
}

// ---------------- main kernel ----------------

#define EPOS(row, col) ((row) * 64 + (((col) + 4 * (row)) & 63))

// FQ[bl][J][d]: uint2 { E[(2J)%32][d], E[(2J+2)%32][d] }, J in [0,32) (J>=16
// duplicates J-16), E[m] = pack_f16(v_m, v_{m+1}). Row stride 130 u32 (pad).
__global__ __launch_bounds__(256, 3) void cin_main(
    const float* __restrict__ x0, const f16* __restrict__ Wfrag,
    const float* __restrict__ b1, const float* __restrict__ W_out,
    const float* __restrict__ rvec, const float* __restrict__ cnst,
    float* __restrict__ out) {
    __shared__ __align__(16) u32 FQ[2 * 32 * 130];  // 33280 B
    __shared__ float eps[2][16 * 64];
    __shared__ float b1s[64], w1s[64], rs[32], rvb[2], obuf[2][2];

    const int t = threadIdx.x;
    const int w = t >> 6, lane = t & 63;
    const int wr = w >> 1, wc = w & 1;
    const int g = (lane >> 4) & 3, l15 = lane & 15;
    const int blk = blockIdx.x;

    {   // stage x0 (2 batches) -> FQ quads, single pass
        const float* src = x0 + (size_t)blk * 4096;
        const int J = t >> 4, l = t & 15;  // J in [0,16)
        int r0 = 2 * J, r1 = 2 * J + 1, r2 = (2 * J + 2) & 31, r3 = (2 * J + 3) & 31;
#pragma unroll
        for (int bl = 0; bl < 2; ++bl) {
            const float* sb = src + bl * 2048;
#pragma unroll
            for (int k2 = 0; k2 < 4; ++k2) {
                int d = 16 * k2 + l;
                U2 u0, u1;
                u0.h2 = __builtin_amdgcn_cvt_pkrtz(sb[r0 * 64 + d], sb[r1 * 64 + d]);
                u1.h2 = __builtin_amdgcn_cvt_pkrtz(sb[r2 * 64 + d], sb[r3 * 64 + d]);
                uint2 ent; ent.x = u0.u; ent.y = u1.u;
                int base = bl * 4160 + J * 130 + 2 * d;
                *reinterpret_cast<uint2*>(&FQ[base]) = ent;
                *reinterpret_cast<uint2*>(&FQ[base + 2080]) = ent;  // J+16 copy
            }
        }
    }
    if (t < 64) { b1s[t] = b1[t]; w1s[t] = W_out[t]; }
    if (t >= 64 && t < 96) rs[t - 64] = rvec[t - 64];
    __syncthreads();

    // single hoisted LDS address; every read = v1base + compile-time imm
    const int v1base = wr * 4160 + 260 * g + 2 * l15;

    U2 xp[4][4], xpsw[4][4];
#pragma unroll
    for (int s = 0; s < 4; ++s) {
        uint2 qa = *reinterpret_cast<const uint2*>(&FQ[v1base + 32 * s]);
        uint2 qb = *reinterpret_cast<const uint2*>(&FQ[v1base + 32 * s + 1040]);
        xp[s][0].u = qa.x; xp[s][1].u = qa.y; xp[s][2].u = qb.x; xp[s][3].u = qb.y;
#pragma unroll
        for (int i = 0; i < 4; ++i)
            xpsw[s][i].u = (xp[s][i].u >> 16) | (xp[s][i].u << 16);
    }

    f32x4 acc[4][4];
#pragma unroll
    for (int s = 0; s < 4; ++s)
#pragma unroll
        for (int tt = 0; tt < 4; ++tt) acc[s][tt] = f32x4{0.f, 0.f, 0.f, 0.f};

    const f16x8* Wg = reinterpret_cast<const f16x8*>(Wfrag);
    f16x8 bfA[4], bfB[4];
#pragma unroll
    for (int tt = 0; tt < 4; ++tt) bfA[tt] = Wg[(wc * 4 + tt) * 64 + lane];

#define PKU(xa, ub) ({ U2 b_; b_.u = (ub); U2 r_; r_.h = (xa).h * b_.h; r_.u; })

#define PREF(dst, cc) { _Pragma("unroll") for (int tt = 0; tt < 4; ++tt) \
    dst[tt] = Wg[((cc) * 8 + wc * 4 + tt) * 64 + lane]; }

#define BODY(cc, bfr) { \
    _Pragma("unroll") \
    for (int s = 0; s < 4; ++s) { \
        AF af; \
        if ((cc) == 0) { \
            _Pragma("unroll") \
            for (int i = 0; i < 4; ++i) af.u[i] = PKU(xp[s][i], xp[s][i].u); \
        } else if ((cc) == 1) { \
            _Pragma("unroll") \
            for (int i = 0; i < 4; ++i) af.u[i] = PKU(xpsw[s][i], xp[s][i].u); \
        } else if ((cc) < 16) { \
            uint2 qa = *reinterpret_cast<const uint2*>(&FQ[v1base + 32 * s + ((cc) >> 1) * 130]); \
            uint2 qb = *reinterpret_cast<const uint2*>(&FQ[v1base + 32 * s + 1040 + ((cc) >> 1) * 130]); \
            if ((cc) & 1) { \
                af.u[0] = PKU(xpsw[s][0], qa.x); af.u[1] = PKU(xpsw[s][1], qa.y); \
                af.u[2] = PKU(xpsw[s][2], qb.x); af.u[3] = PKU(xpsw[s][3], qb.y); \
            } else { \
                af.u[0] = PKU(xp[s][0], qa.x); af.u[1] = PKU(xp[s][1], qa.y); \
                af.u[2] = PKU(xp[s][2], qb.x); af.u[3] = PKU(xp[s][3], qb.y); \
            } \
        } else if ((cc) == 16) { \
            uint2 qa = *reinterpret_cast<const uint2*>(&FQ[v1base + 32 * s + 1040]); \
            af.u[0] = PKU(xp[s][0], qa.x); af.u[1] = PKU(xp[s][1], qa.y); \
            af.u[2] = xp[s][2].u; af.u[3] = xp[s][3].u; \
        } else { \
            uint2 qa = *reinterpret_cast<const uint2*>(&FQ[v1base + 32 * s + 1040]); \
            af.u[0] = PKU(xpsw[s][0], qa.x); af.u[1] = PKU(xpsw[s][1], qa.y); \
            af.u[2] = xp[s][0].u; af.u[3] = xp[s][1].u; \
        } \
        __builtin_amdgcn_s_setprio(1); \
        _Pragma("unroll") \
        for (int tt = 0; tt < 4; ++tt) \
            acc[s][tt] = __builtin_amdgcn_mfma_f32_16x16x32_f16(af.v, bfr[tt], acc[s][tt], 0, 0, 0); \
        __builtin_amdgcn_s_setprio(0); \
    } }

    PREF(bfB, 1);  BODY(0, bfA);
    PREF(bfA, 2);  BODY(1, bfB);
    PREF(bfB, 3);  BODY(2, bfA);
    PREF(bfA, 4);  BODY(3, bfB);
    PREF(bfB, 5);  BODY(4, bfA);
    PREF(bfA, 6);  BODY(5, bfB);
    PREF(bfB, 7);  BODY(6, bfA);
    PREF(bfA, 8);  BODY(7, bfB);
    PREF(bfB, 9);  BODY(8, bfA);
    PREF(bfA, 10); BODY(9, bfB);
    PREF(bfB, 11); BODY(10, bfA);
    PREF(bfA, 12); BODY(11, bfB);
    PREF(bfB, 13); BODY(12, bfA);
    PREF(bfA, 14); BODY(13, bfB);
    PREF(bfB, 15); BODY(14, bfA);
    PREF(bfA, 16); BODY(15, bfB);
    PREF(bfB, 17); BODY(16, bfA);
    BODY(17, bfB);

#undef BODY
#undef PREF
#undef PKU

    // ---- rv term: wc==0 wave handles batch wr
    if (wc == 0) {
        float sum = 0.f;
#pragma unroll
        for (int J = 0; J < 16; ++J) {
            U2 v; v.u = FQ[wr * 4160 + J * 130 + 2 * lane];
            sum += rs[2 * J] * (float)v.h[0] + rs[2 * J + 1] * (float)v.h[1];
        }
#pragma unroll
        for (int off = 32; off; off >>= 1) sum += __shfl_xor(sum, off);
        if (lane == 0) rvb[wr] = sum;
    }

    // ---- epilogue: s(b,d) = sum_h A1*(w1+A2) + b1*A2   (+ b1*w1 in cnst)
    float bs = 0.f;
#pragma unroll
    for (int s = 0; s < 4; ++s) {
        if (wc == 1) {
#pragma unroll
            for (int tt = 0; tt < 4; ++tt) {
                float w1v = w1s[16 * tt + l15];
                float b1v = b1s[16 * tt + l15];
#pragma unroll
                for (int r = 0; r < 4; ++r) {
                    float a = acc[s][tt][r];
                    eps[wr][EPOS(4 * g + r, 16 * tt + l15)] = a + w1v;
                    bs += b1v * a;
                }
            }
        }
        __syncthreads();
        if (wc == 0) {
#pragma unroll
            for (int tt = 0; tt < 4; ++tt)
#pragma unroll
                for (int r = 0; r < 4; ++r)
                    bs += acc[s][tt][r] * eps[wr][EPOS(4 * g + r, 16 * tt + l15)];
        }
        __syncthreads();
    }
#pragma unroll
    for (int off = 32; off; off >>= 1) bs += __shfl_xor(bs, off);
    if (lane == 0) obuf[wr][wc] = bs;
    __syncthreads();
    if (t < 2)
        out[blk * 2 + t] = cnst[0] + rvb[t] + obuf[t][0] + obuf[t][1];
}

extern "C" void kernel_launch(void* const* d_in, const int* in_sizes, int n_in,
                              void* d_out, int out_size, void* d_ws, size_t ws_size,
                              hipStream_t stream) {
    const float* x0    = (const float*)d_in[0];
    const float* W1    = (const float*)d_in[1];
    const float* b1    = (const float*)d_in[2];
    const float* W2    = (const float*)d_in[3];
    const float* b2    = (const float*)d_in[4];
    const float* W3    = (const float*)d_in[5];
    const float* b3    = (const float*)d_in[6];
    const float* W_out = (const float*)d_in[7];
    const float* b_out = (const float*)d_in[8];

    char* wsb = (char*)d_ws;
    f16*   Wfrag = (f16*)wsb;                       // 18*4096 halves = 147456 B
    float* W3effp = (float*)(wsb + 147456);         // 2048 floats
    float* rvecp = W3effp + 2048;                   // 32
    float* cnstp = rvecp + 32;                      // 1
    float* outp  = (float*)d_out;

    hipLaunchKernelGGL(pre_w3eff, dim3(8),   dim3(256), 0, stream, W3, W_out, W3effp);
    hipLaunchKernelGGL(pre_rest,  dim3(129), dim3(256), 0, stream,
                       W1, b1, W2, b2, b3, W_out, b_out, W3effp, Wfrag, rvecp, cnstp);
    hipLaunchKernelGGL(cin_main,  dim3(1024), dim3(256), 0, stream,
                       x0, Wfrag, b1, W_out, rvecp, cnstp, outp);
}